// Round 10
// baseline (316.633 us; speedup 1.0000x reference)
//
#include <hip/hip_runtime.h>
#include <hip/hip_fp16.h>

// GraphEmbedNet: 3-layer GCN, N=50000, E=800000, F=128/128/64.
// R23 (on R22 = 266.4us best): FEATURE-SPLIT aggregation. Evidence: aggs are
// L2-miss-traffic bound (R19->R21 4x MLP only -6.3us; FETCH ~84MB/agg =
// 6.5x the 12.8MB m_buf -> per-XCD 4MiB L2 thrashes on the 12.8MB working
// set). Each agg now runs as two feature-half passes (D=128: 64 feats/pass,
// 6.4MB working set; D=64: 32 feats/pass, 3.2MB) -> ~2x L2 residency.
// Half-0 blocks occupy grid slots [0,nbh) so dispatch order separates the
// phases. Bonus MLP: 8 lanes/edge -> 8 edges per gather instruction (D=128),
// 16 (D=64); a 4-volley puts 32/64 edges in flight -> deg~17 completes in
// ~1 round. Cost: csr header read twice per agg (streamy, cheap).
// VERIFY: agg FETCH_SIZE must drop 84 -> ~60MB, else theory falsified.
// Everything else R22-verbatim (split gemm1 across p1/p2 launches, dinv
// folded into agg, quarter-private p2@1024, LDS-staged p1, R13 sum/scan).

#define K_DIM 128
#define SORT_ITEMS 4096   // elements per pass-1 block

typedef unsigned long long u64;
typedef unsigned int u32;

using half8   = __attribute__((ext_vector_type(8))) _Float16;
using floatx4 = __attribute__((ext_vector_type(4))) float;

// ---------------- sort-based CSR build ----------------

// fused: pack edges + self-loops AND per-block 256-bin hist of high byte.
// blocks [nb, nb+nwb): convert W1|W2|W3 fp32 -> fp16 instead.
__global__ void build_hist(const int* __restrict__ row, const int* __restrict__ col,
                           const float* __restrict__ ew, u64* __restrict__ el,
                           u32* __restrict__ ghist, int E, int N, int nb,
                           const float* __restrict__ W1, const float* __restrict__ W2,
                           const float* __restrict__ W3, __half* __restrict__ Wh,
                           int nw1, int nw2, int nw3) {
    const int b = blockIdx.x;
    if (b >= nb) {
        const int i = (b - nb) * 256 + threadIdx.x;
        const int tot = nw1 + nw2 + nw3;
        if (i < tot) {
            float v = (i < nw1) ? W1[i] : (i < nw1 + nw2 ? W2[i - nw1] : W3[i - nw1 - nw2]);
            Wh[i] = __float2half_rn(v);
        }
        return;
    }
    __shared__ u32 bin[256];
    bin[threadIdx.x] = 0;
    __syncthreads();
    const int total = E + N;
    const int base = b * SORT_ITEMS;
    const int end = min(base + SORT_ITEMS, total);
    for (int i = base + threadIdx.x; i < end; i += 256) {
        u64 e;
        if (i < E) {
            e = ((u64)(u32)col[i] << 48) | ((u64)(u32)row[i] << 32)
              | (u64)__float_as_uint(ew[i]);
        } else {
            int v = i - E;
            e = ((u64)(u32)v << 48) | ((u64)(u32)v << 32)
              | (u64)__float_as_uint(1.0f);
        }
        el[i] = e;
        atomicAdd(&bin[(u32)(e >> 56)], 1u);
    }
    __syncthreads();
    ghist[(size_t)threadIdx.x * nb + b] = bin[threadIdx.x];
}

// block d reduces ghist[d*nb .. d*nb+nb) -> dsum[d]   (R13 form)
__global__ void digit_sum(const u32* __restrict__ ghist, u32* __restrict__ dsum, int nb) {
    __shared__ u32 s[256];
    const int d = blockIdx.x;
    u32 acc = 0;
    for (int i = threadIdx.x; i < nb; i += 256) acc += ghist[(size_t)d * nb + i];
    s[threadIdx.x] = acc;
    __syncthreads();
    for (int off = 128; off > 0; off >>= 1) {
        if (threadIdx.x < off) s[threadIdx.x] += s[threadIdx.x + off];
        __syncthreads();
    }
    if (threadIdx.x == 0) dsum[d] = s[0];
}

// block d: re-scan dsum in LDS for its digit base, write dbase[d] (+[256]),
// then exclusive-scan its nb block-counts in place.   (R13 form)
__global__ void digit_scan(u32* __restrict__ ghist, const u32* __restrict__ dsum,
                           u32* __restrict__ dbase, int nb) {
    __shared__ u32 ds[256];
    __shared__ u32 s[256];
    const int d = blockIdx.x, t = threadIdx.x;
    ds[t] = dsum[t];
    __syncthreads();
    for (int off = 1; off < 256; off <<= 1) {
        u32 u = (t >= off) ? ds[t - off] : 0;
        __syncthreads();
        ds[t] += u;
        __syncthreads();
    }
    u32 carry = (d == 0) ? 0u : ds[d - 1];   // exclusive digit base
    if (t == 0) dbase[d] = carry;
    if (d == 255 && t == 0) dbase[256] = ds[255];
    for (int base = 0; base < nb; base += 256) {
        const int i = base + t;
        const u32 v = (i < nb) ? ghist[(size_t)d * nb + i] : 0;
        s[t] = v;
        __syncthreads();
        for (int off = 1; off < 256; off <<= 1) {
            u32 u = (t >= off) ? s[t - off] : 0;
            __syncthreads();
            s[t] += u;
            __syncthreads();
        }
        if (i < nb) ghist[(size_t)d * nb + i] = carry + s[t] - v;
        carry += s[255];
        __syncthreads();
    }
}

// ---------------- merged pass-1 scatter + gemm1 front half ----------------
// blocks [0, nb): LDS-staged coalesced scatter (R16 form).
// blocks [nb, nb+g1): 4-wave 64-row MFMA tile, m_raw = fp16(x @ W1^T).
__global__ __launch_bounds__(256) void p1_gemm(const u64* __restrict__ el,
                                               const u32* __restrict__ ghist,
                                               u64* __restrict__ out, int total, int nb,
                                               const float* __restrict__ x,
                                               const __half* __restrict__ Wh,
                                               __half* __restrict__ C, int n) {
    __shared__ u32 gbase[256];
    __shared__ u32 lbase[256];
    __shared__ u32 lcur[256];
    __shared__ u64 buf[SORT_ITEMS];
    if ((int)blockIdx.x >= nb) {
        // ---- gemm tile: 4 waves x 16 rows, BN=128, fp32 input ----
        const int gb = blockIdx.x - nb;
        const int wave = threadIdx.x >> 6;
        const int lane = threadIdx.x & 63;
        const int quad = lane >> 4;
        const int l16  = lane & 15;
        const int row0 = gb * 64 + wave * 16;

        int arow = row0 + l16;
        if (arow > n - 1) arow = n - 1;

        floatx4 acc[8] = {};
#pragma unroll
        for (int kc = 0; kc < 4; ++kc) {
            const int kof = kc * 32 + quad * 8;
            const float* ap = x + (size_t)arow * K_DIM + kof;
            float4 f0 = *(const float4*)ap;
            float4 f1 = *(const float4*)(ap + 4);
            half8 af;
            af[0] = (_Float16)f0.x; af[1] = (_Float16)f0.y;
            af[2] = (_Float16)f0.z; af[3] = (_Float16)f0.w;
            af[4] = (_Float16)f1.x; af[5] = (_Float16)f1.y;
            af[6] = (_Float16)f1.z; af[7] = (_Float16)f1.w;
#pragma unroll
            for (int ct = 0; ct < 8; ++ct) {
                half8 bf = *(const half8*)(Wh + (size_t)(ct * 16 + l16) * K_DIM + kof);
                acc[ct] = __builtin_amdgcn_mfma_f32_16x16x32_f16(af, bf, acc[ct], 0, 0, 0);
            }
        }
        int grow[4];
        bool okr[4];
#pragma unroll
        for (int r = 0; r < 4; ++r) {
            grow[r] = row0 + quad * 4 + r;
            okr[r] = grow[r] < n;
        }
#pragma unroll
        for (int ct = 0; ct < 8; ++ct) {
            const int colb = ct * 16 + l16;
#pragma unroll
            for (int r = 0; r < 4; ++r)
                if (okr[r])
                    C[(size_t)grow[r] * 128 + colb] = __float2half_rn(acc[ct][r]);
        }
        return;
    }
    const int t = threadIdx.x;
    gbase[t] = ghist[(size_t)t * nb + blockIdx.x];
    lcur[t] = 0;                       // used as histogram first
    __syncthreads();
    const int base = blockIdx.x * SORT_ITEMS;
    const int end = min(base + SORT_ITEMS, total);
    const int cnt = end - base;

    u64 it[16];
    bool ok[16];
#pragma unroll
    for (int j = 0; j < 16; ++j) {
        const int i = base + t + j * 256;
        ok[j] = i < end;
        it[j] = ok[j] ? el[i] : 0;
        if (ok[j]) atomicAdd(&lcur[(u32)(it[j] >> 56)], 1u);
    }
    __syncthreads();
    const u32 v = lcur[t];
    lbase[t] = v;
    __syncthreads();
    for (int off = 1; off < 256; off <<= 1) {
        u32 u = (t >= off) ? lbase[t - off] : 0;
        __syncthreads();
        lbase[t] += u;
        __syncthreads();
    }
    const u32 excl = lbase[t] - v;     // exclusive local base for digit t
    __syncthreads();
    lbase[t] = excl;
    lcur[t] = excl;
    __syncthreads();
#pragma unroll
    for (int j = 0; j < 16; ++j) {
        if (ok[j]) {
            const u32 d = (u32)(it[j] >> 56);
            const u32 p = atomicAdd(&lcur[d], 1u);
            buf[p] = it[j];
        }
    }
    __syncthreads();
    for (int i = t; i < cnt; i += 256) {
        const u64 e = buf[i];
        const u32 d = (u32)(e >> 56);
        out[gbase[d] + i - lbase[d]] = e;
    }
}

// ---------------- merged pass 2 + gemm1 back half ----------------
__global__ __launch_bounds__(1024) void p2_gemm(
        const u64* __restrict__ in, u64* __restrict__ out,
        const u32* __restrict__ dbase,
        int* __restrict__ offs, float* __restrict__ dinv, int n, int ngroups,
        const float* __restrict__ x, const __half* __restrict__ Wh,
        __half* __restrict__ C, int rowoff) {
    if ((int)blockIdx.x < ngroups) {
        // ---- p2 quarter-private sort ----
        const int t = threadIdx.x;
        const int q = t >> 8;          // quarter 0..3
        const int b = t & 255;
        const int base = (int)dbase[blockIdx.x];
        const int size = (int)dbase[blockIdx.x + 1] - base;
        __shared__ u32 hist[4][256];
        __shared__ u32 cur[4][256];
        __shared__ u32 s[256];
        __shared__ float wsum[4][256];
        hist[q][b] = 0;
        wsum[q][b] = 0.f;
        __syncthreads();
        for (int i = t; i < size; i += 1024)
            atomicAdd(&hist[q][(u32)(in[base + i] >> 48) & 0xFFu], 1u);
        __syncthreads();
        u32 v = 0;
        if (t < 256) {
            v = hist[0][b] + hist[1][b] + hist[2][b] + hist[3][b];
            s[b] = v;
        }
        __syncthreads();
        for (int off = 1; off < 256; off <<= 1) {
            u32 u = (t < 256 && b >= off) ? s[b - off] : 0;
            __syncthreads();
            if (t < 256) s[b] += u;
            __syncthreads();
        }
        u32 mystart = 0;
        if (t < 256) {
            mystart = (u32)base + s[b] - v;   // node (blockIdx*256+b)'s run start
            u32 c = mystart;
            cur[0][b] = c; c += hist[0][b];
            cur[1][b] = c; c += hist[1][b];
            cur[2][b] = c; c += hist[2][b];
            cur[3][b] = c;
        }
        __syncthreads();
        for (int i = t; i < size; i += 1024) {
            u64 e = in[base + i];
            u32 lo = (u32)(e >> 48) & 0xFFu;
            u32 p = atomicAdd(&cur[q][lo], 1u);
            out[p] = e;
            atomicAdd(&wsum[q][lo], __uint_as_float((u32)(e & 0xFFFFFFFFu)));
        }
        __syncthreads();
        const int node = blockIdx.x * 256 + b;
        if (t < 256 && node < n && v > 0) {
            offs[node] = (int)mystart;
            dinv[node] = rsqrtf(wsum[0][b] + wsum[1][b] + wsum[2][b] + wsum[3][b]);
            if (node == n - 1) offs[n] = (int)(mystart + v);
        }
    } else {
        // ---- gemm tile: 16 waves x 16 rows, BN=128, fp32 input ----
        const int gb = blockIdx.x - ngroups;
        const int wave = threadIdx.x >> 6;
        const int lane = threadIdx.x & 63;
        const int quad = lane >> 4;
        const int l16  = lane & 15;
        const int row0 = rowoff + gb * 256 + wave * 16;

        int arow = row0 + l16;
        if (arow > n - 1) arow = n - 1;

        floatx4 acc[8] = {};
#pragma unroll
        for (int kc = 0; kc < 4; ++kc) {
            const int kof = kc * 32 + quad * 8;
            const float* ap = x + (size_t)arow * K_DIM + kof;
            float4 f0 = *(const float4*)ap;
            float4 f1 = *(const float4*)(ap + 4);
            half8 af;
            af[0] = (_Float16)f0.x; af[1] = (_Float16)f0.y;
            af[2] = (_Float16)f0.z; af[3] = (_Float16)f0.w;
            af[4] = (_Float16)f1.x; af[5] = (_Float16)f1.y;
            af[6] = (_Float16)f1.z; af[7] = (_Float16)f1.w;
#pragma unroll
            for (int ct = 0; ct < 8; ++ct) {
                half8 bf = *(const half8*)(Wh + (size_t)(ct * 16 + l16) * K_DIM + kof);
                acc[ct] = __builtin_amdgcn_mfma_f32_16x16x32_f16(af, bf, acc[ct], 0, 0, 0);
            }
        }
        int grow[4];
        bool ok[4];
#pragma unroll
        for (int r = 0; r < 4; ++r) {
            grow[r] = row0 + quad * 4 + r;
            ok[r] = grow[r] < n;
        }
#pragma unroll
        for (int ct = 0; ct < 8; ++ct) {
            const int colb = ct * 16 + l16;
#pragma unroll
            for (int r = 0; r < 4; ++r)
                if (ok[r])
                    C[(size_t)grow[r] * 128 + colb] = __float2half_rn(acc[ct][r]);
        }
    }
}

// ---------------- MFMA GEMM (layers 2,3): C[n][o] = half(sum_k A[n][k]*W[o][k]) ----------------

template <int BN>
__global__ __launch_bounds__(256) void mfma_gemm(const __half* __restrict__ Ain,
                                                 const __half* __restrict__ Wh,
                                                 __half* __restrict__ C, int nrows) {
    constexpr int NT = BN / 16;
    const int wave = threadIdx.x >> 6;
    const int lane = threadIdx.x & 63;
    const int quad = lane >> 4;
    const int l16  = lane & 15;
    const int row0 = blockIdx.x * 64 + wave * 16;

    int arow = row0 + l16;
    if (arow > nrows - 1) arow = nrows - 1;

    floatx4 acc[NT] = {};

#pragma unroll
    for (int kc = 0; kc < 4; ++kc) {
        const int kof = kc * 32 + quad * 8;
        half8 af = *(const half8*)(Ain + (size_t)arow * K_DIM + kof);
#pragma unroll
        for (int ct = 0; ct < NT; ++ct) {
            half8 bf = *(const half8*)(Wh + (size_t)(ct * 16 + l16) * K_DIM + kof);
            acc[ct] = __builtin_amdgcn_mfma_f32_16x16x32_f16(af, bf, acc[ct], 0, 0, 0);
        }
    }

    int grow[4];
    bool ok[4];
#pragma unroll
    for (int r = 0; r < 4; ++r) {
        grow[r] = row0 + quad * 4 + r;
        ok[r] = grow[r] < nrows;
    }
#pragma unroll
    for (int ct = 0; ct < NT; ++ct) {
        const int colb = ct * 16 + l16;
#pragma unroll
        for (int r = 0; r < 4; ++r)
            if (ok[r])
                C[(size_t)grow[r] * BN + colb] = __float2half_rn(acc[ct][r]);
    }
}

// ---------------- aggregation (feature-split) ----------------
// out[i] = relu(bias + dinv[i] * sum_e (ew_e * dinv[src_e]) * m_raw[src_e])
// Grid = 2 x nbh blocks; blocks [0,nbh) do feature-half 0, [nbh,2*nbh)
// half 1. Per-pass working set = D/2 features (6.4MB / 3.2MB) -> L2-resident.
// D=128: 8 lanes/edge (8 feats each) -> 8 edges/gather, 4-volley = 32 in
// flight. D=64: 4 lanes/edge -> 16 edges/gather, 4-volley = 64 in flight.

template <int D, typename OUT>
__global__ __launch_bounds__(256) void agg_kernel(
    const __half* __restrict__ m, const int* __restrict__ offs,
    const int2* __restrict__ csr, const float* __restrict__ dinv,
    const float* __restrict__ bias, OUT* __restrict__ out, int n) {
    const int nbh = (n + 3) >> 2;
    const int half = ((int)blockIdx.x >= nbh) ? 1 : 0;
    const int blk = blockIdx.x - half * nbh;
    const int wid = threadIdx.x >> 6;
    const int lane = threadIdx.x & 63;
    const int node = (blk << 2) + wid;
    if (node >= n) return;
    const int beg = offs[node];
    const int end = offs[node + 1];
    const int cnt = end - beg;          // >= 1 (self-loop)
    const half8* mrow = (const half8*)m;

    // one coalesced load fetches up to 64 csr entries for this node
    const int2 ev = csr[beg + min(lane, cnt - 1)];
    const int   sv = ev.y & 0xFFFF;
    const float ds = dinv[sv];                      // L2-hot (200KB table)
    const float wv = (lane < cnt) ? __int_as_float(ev.x) * ds : 0.f;
    const int nr = min(cnt, 64);

    float acc[8] = {0.f, 0.f, 0.f, 0.f, 0.f, 0.f, 0.f, 0.f};

    if constexpr (D == 128) {
        // 8 lanes cover 64 features of this half; octet = edge slot
        const int oct = lane >> 3;
        const int l8  = lane & 7;
        const int hb  = half * 8;      // half8 offset within 16-unit row
        const int rem = nr & 31;
        if (rem) {
            float w0 = __shfl(wv, oct),       w1 = __shfl(wv, 8 + oct);
            float w2 = __shfl(wv, 16 + oct),  w3 = __shfl(wv, 24 + oct);
            int   s0 = __shfl(sv, oct),       s1 = __shfl(sv, 8 + oct);
            int   s2 = __shfl(sv, 16 + oct),  s3 = __shfl(sv, 24 + oct);
            w0 = (oct      < rem) ? w0 : 0.f;
            w1 = (8 + oct  < rem) ? w1 : 0.f;
            w2 = (16 + oct < rem) ? w2 : 0.f;
            w3 = (24 + oct < rem) ? w3 : 0.f;
            half8 h0 = mrow[(size_t)s0 * 16 + hb + l8];
            half8 h1 = mrow[(size_t)s1 * 16 + hb + l8];
            half8 h2 = mrow[(size_t)s2 * 16 + hb + l8];
            half8 h3 = mrow[(size_t)s3 * 16 + hb + l8];
#pragma unroll
            for (int i = 0; i < 8; ++i) {
                acc[i] = fmaf(w0, (float)h0[i], acc[i]);
                acc[i] = fmaf(w1, (float)h1[i], acc[i]);
                acc[i] = fmaf(w2, (float)h2[i], acc[i]);
                acc[i] = fmaf(w3, (float)h3[i], acc[i]);
            }
        }
        for (int k = rem; k < nr; k += 32) {
            float w0 = __shfl(wv, k + oct),       w1 = __shfl(wv, k + 8 + oct);
            float w2 = __shfl(wv, k + 16 + oct),  w3 = __shfl(wv, k + 24 + oct);
            int   s0 = __shfl(sv, k + oct),       s1 = __shfl(sv, k + 8 + oct);
            int   s2 = __shfl(sv, k + 16 + oct),  s3 = __shfl(sv, k + 24 + oct);
            half8 h0 = mrow[(size_t)s0 * 16 + hb + l8];
            half8 h1 = mrow[(size_t)s1 * 16 + hb + l8];
            half8 h2 = mrow[(size_t)s2 * 16 + hb + l8];
            half8 h3 = mrow[(size_t)s3 * 16 + hb + l8];
#pragma unroll
            for (int i = 0; i < 8; ++i) {
                acc[i] = fmaf(w0, (float)h0[i], acc[i]);
                acc[i] = fmaf(w1, (float)h1[i], acc[i]);
                acc[i] = fmaf(w2, (float)h2[i], acc[i]);
                acc[i] = fmaf(w3, (float)h3[i], acc[i]);
            }
        }
        // rare: degree > 64 tail, per-octet strided
        for (int k = beg + 64 + oct; k < end; k += 8) {
            const int2 e0 = csr[k];
            const int  s0 = e0.y & 0xFFFF;
            const float w0 = __int_as_float(e0.x) * dinv[s0];
            half8 hv = mrow[(size_t)s0 * 16 + hb + l8];
#pragma unroll
            for (int i = 0; i < 8; ++i)
                acc[i] = fmaf(w0, (float)hv[i], acc[i]);
        }
#pragma unroll
        for (int i = 0; i < 8; ++i) {
            acc[i] += __shfl_xor(acc[i], 8);
            acc[i] += __shfl_xor(acc[i], 16);
            acc[i] += __shfl_xor(acc[i], 32);
        }
        if (oct == 0) {
            const float dv = dinv[node];
            const float* bp = bias + half * 64 + l8 * 8;
            const float4 b0 = *(const float4*)bp;
            const float4 b1 = *(const float4*)(bp + 4);
            const float bb[8] = {b0.x, b0.y, b0.z, b0.w, b1.x, b1.y, b1.z, b1.w};
            half8 ho;
#pragma unroll
            for (int i = 0; i < 8; ++i)
                ho[i] = (_Float16)fmaxf(acc[i] * dv + bb[i], 0.f);
            *(half8*)((__half*)out + (size_t)node * 128 + half * 64 + l8 * 8) = ho;
        }
    } else {
        // D == 64: 4 lanes cover 32 features of this half; grp = edge slot
        const int grp = lane >> 2;
        const int l4  = lane & 3;
        const int hb  = half * 4;      // half8 offset within 8-unit row
        const int rem = nr & 63;
        if (rem) {
            float w0 = __shfl(wv, grp),       w1 = __shfl(wv, 16 + grp);
            float w2 = __shfl(wv, 32 + grp),  w3 = __shfl(wv, 48 + grp);
            int   s0 = __shfl(sv, grp),       s1 = __shfl(sv, 16 + grp);
            int   s2 = __shfl(sv, 32 + grp),  s3 = __shfl(sv, 48 + grp);
            w0 = (grp      < rem) ? w0 : 0.f;
            w1 = (16 + grp < rem) ? w1 : 0.f;
            w2 = (32 + grp < rem) ? w2 : 0.f;
            w3 = (48 + grp < rem) ? w3 : 0.f;
            half8 h0 = mrow[(size_t)s0 * 8 + hb + l4];
            half8 h1 = mrow[(size_t)s1 * 8 + hb + l4];
            half8 h2 = mrow[(size_t)s2 * 8 + hb + l4];
            half8 h3 = mrow[(size_t)s3 * 8 + hb + l4];
#pragma unroll
            for (int i = 0; i < 8; ++i) {
                acc[i] = fmaf(w0, (float)h0[i], acc[i]);
                acc[i] = fmaf(w1, (float)h1[i], acc[i]);
                acc[i] = fmaf(w2, (float)h2[i], acc[i]);
                acc[i] = fmaf(w3, (float)h3[i], acc[i]);
            }
        }
        if (rem < nr) {
            // nr == 64, rem == 0: one full 64-edge volley
            float w0 = __shfl(wv, grp),       w1 = __shfl(wv, 16 + grp);
            float w2 = __shfl(wv, 32 + grp),  w3 = __shfl(wv, 48 + grp);
            int   s0 = __shfl(sv, grp),       s1 = __shfl(sv, 16 + grp);
            int   s2 = __shfl(sv, 32 + grp),  s3 = __shfl(sv, 48 + grp);
            half8 h0 = mrow[(size_t)s0 * 8 + hb + l4];
            half8 h1 = mrow[(size_t)s1 * 8 + hb + l4];
            half8 h2 = mrow[(size_t)s2 * 8 + hb + l4];
            half8 h3 = mrow[(size_t)s3 * 8 + hb + l4];
#pragma unroll
            for (int i = 0; i < 8; ++i) {
                acc[i] = fmaf(w0, (float)h0[i], acc[i]);
                acc[i] = fmaf(w1, (float)h1[i], acc[i]);
                acc[i] = fmaf(w2, (float)h2[i], acc[i]);
                acc[i] = fmaf(w3, (float)h3[i], acc[i]);
            }
        }
        // rare: degree > 64 tail, per-group strided
        for (int k = beg + 64 + grp; k < end; k += 16) {
            const int2 e0 = csr[k];
            const int  s0 = e0.y & 0xFFFF;
            const float w0 = __int_as_float(e0.x) * dinv[s0];
            half8 hv = mrow[(size_t)s0 * 8 + hb + l4];
#pragma unroll
            for (int i = 0; i < 8; ++i)
                acc[i] = fmaf(w0, (float)hv[i], acc[i]);
        }
#pragma unroll
        for (int i = 0; i < 8; ++i) {
            acc[i] += __shfl_xor(acc[i], 4);
            acc[i] += __shfl_xor(acc[i], 8);
            acc[i] += __shfl_xor(acc[i], 16);
            acc[i] += __shfl_xor(acc[i], 32);
        }
        if (grp == 0) {
            const float dv = dinv[node];
            const float* bp = bias + half * 32 + l4 * 8;
            const float4 b0 = *(const float4*)bp;
            const float4 b1 = *(const float4*)(bp + 4);
            float4 v0, v1;
            v0.x = fmaxf(acc[0] * dv + b0.x, 0.f);
            v0.y = fmaxf(acc[1] * dv + b0.y, 0.f);
            v0.z = fmaxf(acc[2] * dv + b0.z, 0.f);
            v0.w = fmaxf(acc[3] * dv + b0.w, 0.f);
            v1.x = fmaxf(acc[4] * dv + b1.x, 0.f);
            v1.y = fmaxf(acc[5] * dv + b1.y, 0.f);
            v1.z = fmaxf(acc[6] * dv + b1.z, 0.f);
            v1.w = fmaxf(acc[7] * dv + b1.w, 0.f);
            float* op = (float*)out + (size_t)node * 64 + half * 32 + l4 * 8;
            *(float4*)op = v0;
            *(float4*)(op + 4) = v1;
        }
    }
}

// ---------------- launch ----------------

extern "C" void kernel_launch(void* const* d_in, const int* in_sizes, int n_in,
                              void* d_out, int out_size, void* d_ws, size_t ws_size,
                              hipStream_t stream) {
    const float* x  = (const float*)d_in[0];
    const int*   ei = (const int*)d_in[1];   // [2, E] int32
    const float* ew = (const float*)d_in[2];
    const float* W1 = (const float*)d_in[3];
    const float* b1 = (const float*)d_in[4];
    const float* W2 = (const float*)d_in[5];
    const float* b2 = (const float*)d_in[6];
    const float* W3 = (const float*)d_in[7];
    const float* b3 = (const float*)d_in[8];
    float* out = (float*)d_out;

    const int N = in_sizes[0] / K_DIM;      // 50000
    const int E = in_sizes[2];              // 800000
    const int* row = ei;                    // edge_index[0] (source)
    const int* col = ei + E;                // edge_index[1] (target / aggregation)

    const int total = E + N;                         // 850000
    const int nb = (total + SORT_ITEMS - 1) / SORT_ITEMS;   // 208
    const int ngroups = (N + 255) >> 8;              // 196 high-byte groups
    const int NW1 = 128 * 128, NW2 = 128 * 128, NW3 = 64 * 128;
    const int nwb = (NW1 + NW2 + NW3 + 255) / 256;   // 160 weight-convert blocks

    // workspace layout, 8B-aligned sections first
    u64* elA      = (u64*)d_ws;                                // total
    u64* elB      = elA + total;                               // total
    __half* m_buf = (__half*)(elB + total);                    // N*128 fp16
    __half* h_buf = m_buf + (size_t)N * K_DIM;                 // N*128 fp16
    __half* Wh    = h_buf + (size_t)N * K_DIM;                 // 40960 fp16
    u32* ghist    = (u32*)(Wh + NW1 + NW2 + NW3);              // 256*nb
    u32* dsum     = ghist + (size_t)256 * nb;                  // 256
    u32* dbase    = dsum + 256;                                // 257
    int* offs     = (int*)(dbase + 257);                       // N+1
    float* dinv   = (float*)(offs + N + 1);                    // N

    build_hist<<<nb + nwb, 256, 0, stream>>>(row, col, ew, elA, ghist, E, N, nb,
                                             W1, W2, W3, Wh, NW1, NW2, NW3);
    digit_sum<<<256, 256, 0, stream>>>(ghist, dsum, nb);
    digit_scan<<<256, 256, 0, stream>>>(ghist, dsum, dbase, nb);

    // gemm1 front half rides in the p1 launch: rows [0, g1rows)
    const int g1blocks = 392;                        // 64-row tiles
    const int g1rows = g1blocks * 64;                // 25088
    p1_gemm<<<nb + g1blocks, 256, 0, stream>>>(elA, ghist, elB, total, nb,
                                               x, Wh, m_buf, N);

    // gemm1 back half rides in the p2 launch: rows [g1rows, N)
    const int g2blocks = (N - g1rows + 255) / 256;   // 98 16-wave tiles
    p2_gemm<<<ngroups + g2blocks, 1024, 0, stream>>>(
        elB, elA, dbase, offs, dinv, N, ngroups, x, Wh, m_buf, g1rows);

    const int gemm_blocks = (N + 63) / 64;
    const int agg_blocks2 = 2 * ((N + 3) / 4);       // feature-split: 2x blocks
    const int2* csr = (const int2*)elA;

    // layer 1 agg: h = fp16(relu(dinv_n * sum (ew*dinv_s)*m_raw + b1))
    agg_kernel<128, __half><<<agg_blocks2, 256, 0, stream>>>(m_buf, offs, csr, dinv, b1, h_buf, N);
    // layer 2
    mfma_gemm<128><<<gemm_blocks, 256, 0, stream>>>(h_buf, Wh + NW1, m_buf, N);
    agg_kernel<128, __half><<<agg_blocks2, 256, 0, stream>>>(m_buf, offs, csr, dinv, b2, h_buf, N);
    // layer 3: F_OUT=64, write d_out (fp32) directly
    mfma_gemm<64><<<gemm_blocks, 256, 0, stream>>>(h_buf, Wh + NW1 + NW2, m_buf, N);
    agg_kernel<64, float><<<agg_blocks2, 256, 0, stream>>>(m_buf, offs, csr, dinv, b3, out, N);
}

// Round 11
// 271.491 us; speedup vs baseline: 1.1663x; 1.1663x over previous
//
#include <hip/hip_runtime.h>
#include <hip/hip_fp16.h>

// GraphEmbedNet: 3-layer GCN, N=50000, E=800000, F=128/128/64.
// R24 = REVERT to R22 byte-exact (266.4us, best verified).
// R23's feature-split agg FALSIFIED: FETCH dropped 84->66MB as predicted
// (locality mechanism real) but dur went 30->52us/agg -- VALUBusy hit 58-60%
// (doubled per-node header work + deeper reduce + ~47% dummy gather slots at
// deg~17). Ledger after 6 agg-structure variants: aggs are neither
// latency-bound (R21: 4x MLP -> -6us) nor fetch-bound (R23: -21% traffic ->
// +70% time); R21/R22 volley form is the structural optimum (~30us each).
// Remaining budget: fills ~88us (harness), aggs ~90us, sort+gemm1 ~45us
// (phase-overlapped), gemm2/3 ~15us, gaps ~10us.

#define K_DIM 128
#define SORT_ITEMS 4096   // elements per pass-1 block

typedef unsigned long long u64;
typedef unsigned int u32;

using half8   = __attribute__((ext_vector_type(8))) _Float16;
using floatx4 = __attribute__((ext_vector_type(4))) float;

// ---------------- sort-based CSR build ----------------

// fused: pack edges + self-loops AND per-block 256-bin hist of high byte.
// blocks [nb, nb+nwb): convert W1|W2|W3 fp32 -> fp16 instead.
__global__ void build_hist(const int* __restrict__ row, const int* __restrict__ col,
                           const float* __restrict__ ew, u64* __restrict__ el,
                           u32* __restrict__ ghist, int E, int N, int nb,
                           const float* __restrict__ W1, const float* __restrict__ W2,
                           const float* __restrict__ W3, __half* __restrict__ Wh,
                           int nw1, int nw2, int nw3) {
    const int b = blockIdx.x;
    if (b >= nb) {
        const int i = (b - nb) * 256 + threadIdx.x;
        const int tot = nw1 + nw2 + nw3;
        if (i < tot) {
            float v = (i < nw1) ? W1[i] : (i < nw1 + nw2 ? W2[i - nw1] : W3[i - nw1 - nw2]);
            Wh[i] = __float2half_rn(v);
        }
        return;
    }
    __shared__ u32 bin[256];
    bin[threadIdx.x] = 0;
    __syncthreads();
    const int total = E + N;
    const int base = b * SORT_ITEMS;
    const int end = min(base + SORT_ITEMS, total);
    for (int i = base + threadIdx.x; i < end; i += 256) {
        u64 e;
        if (i < E) {
            e = ((u64)(u32)col[i] << 48) | ((u64)(u32)row[i] << 32)
              | (u64)__float_as_uint(ew[i]);
        } else {
            int v = i - E;
            e = ((u64)(u32)v << 48) | ((u64)(u32)v << 32)
              | (u64)__float_as_uint(1.0f);
        }
        el[i] = e;
        atomicAdd(&bin[(u32)(e >> 56)], 1u);
    }
    __syncthreads();
    ghist[(size_t)threadIdx.x * nb + b] = bin[threadIdx.x];
}

// block d reduces ghist[d*nb .. d*nb+nb) -> dsum[d]   (R13 form)
__global__ void digit_sum(const u32* __restrict__ ghist, u32* __restrict__ dsum, int nb) {
    __shared__ u32 s[256];
    const int d = blockIdx.x;
    u32 acc = 0;
    for (int i = threadIdx.x; i < nb; i += 256) acc += ghist[(size_t)d * nb + i];
    s[threadIdx.x] = acc;
    __syncthreads();
    for (int off = 128; off > 0; off >>= 1) {
        if (threadIdx.x < off) s[threadIdx.x] += s[threadIdx.x + off];
        __syncthreads();
    }
    if (threadIdx.x == 0) dsum[d] = s[0];
}

// block d: re-scan dsum in LDS for its digit base, write dbase[d] (+[256]),
// then exclusive-scan its nb block-counts in place.   (R13 form)
__global__ void digit_scan(u32* __restrict__ ghist, const u32* __restrict__ dsum,
                           u32* __restrict__ dbase, int nb) {
    __shared__ u32 ds[256];
    __shared__ u32 s[256];
    const int d = blockIdx.x, t = threadIdx.x;
    ds[t] = dsum[t];
    __syncthreads();
    for (int off = 1; off < 256; off <<= 1) {
        u32 u = (t >= off) ? ds[t - off] : 0;
        __syncthreads();
        ds[t] += u;
        __syncthreads();
    }
    u32 carry = (d == 0) ? 0u : ds[d - 1];   // exclusive digit base
    if (t == 0) dbase[d] = carry;
    if (d == 255 && t == 0) dbase[256] = ds[255];
    for (int base = 0; base < nb; base += 256) {
        const int i = base + t;
        const u32 v = (i < nb) ? ghist[(size_t)d * nb + i] : 0;
        s[t] = v;
        __syncthreads();
        for (int off = 1; off < 256; off <<= 1) {
            u32 u = (t >= off) ? s[t - off] : 0;
            __syncthreads();
            s[t] += u;
            __syncthreads();
        }
        if (i < nb) ghist[(size_t)d * nb + i] = carry + s[t] - v;
        carry += s[255];
        __syncthreads();
    }
}

// ---------------- merged pass-1 scatter + gemm1 front half ----------------
// blocks [0, nb): LDS-staged coalesced scatter (R16 form).
// blocks [nb, nb+g1): 4-wave 64-row MFMA tile, m_raw = fp16(x @ W1^T),
//   rows (b-nb)*64 .. +64. Wh ready (build_hist completed 2 launches ago).
__global__ __launch_bounds__(256) void p1_gemm(const u64* __restrict__ el,
                                               const u32* __restrict__ ghist,
                                               u64* __restrict__ out, int total, int nb,
                                               const float* __restrict__ x,
                                               const __half* __restrict__ Wh,
                                               __half* __restrict__ C, int n) {
    __shared__ u32 gbase[256];
    __shared__ u32 lbase[256];
    __shared__ u32 lcur[256];
    __shared__ u64 buf[SORT_ITEMS];
    if ((int)blockIdx.x >= nb) {
        // ---- gemm tile: 4 waves x 16 rows, BN=128, fp32 input ----
        const int gb = blockIdx.x - nb;
        const int wave = threadIdx.x >> 6;
        const int lane = threadIdx.x & 63;
        const int quad = lane >> 4;
        const int l16  = lane & 15;
        const int row0 = gb * 64 + wave * 16;

        int arow = row0 + l16;
        if (arow > n - 1) arow = n - 1;

        floatx4 acc[8] = {};
#pragma unroll
        for (int kc = 0; kc < 4; ++kc) {
            const int kof = kc * 32 + quad * 8;
            const float* ap = x + (size_t)arow * K_DIM + kof;
            float4 f0 = *(const float4*)ap;
            float4 f1 = *(const float4*)(ap + 4);
            half8 af;
            af[0] = (_Float16)f0.x; af[1] = (_Float16)f0.y;
            af[2] = (_Float16)f0.z; af[3] = (_Float16)f0.w;
            af[4] = (_Float16)f1.x; af[5] = (_Float16)f1.y;
            af[6] = (_Float16)f1.z; af[7] = (_Float16)f1.w;
#pragma unroll
            for (int ct = 0; ct < 8; ++ct) {
                half8 bf = *(const half8*)(Wh + (size_t)(ct * 16 + l16) * K_DIM + kof);
                acc[ct] = __builtin_amdgcn_mfma_f32_16x16x32_f16(af, bf, acc[ct], 0, 0, 0);
            }
        }
        int grow[4];
        bool okr[4];
#pragma unroll
        for (int r = 0; r < 4; ++r) {
            grow[r] = row0 + quad * 4 + r;
            okr[r] = grow[r] < n;
        }
#pragma unroll
        for (int ct = 0; ct < 8; ++ct) {
            const int colb = ct * 16 + l16;
#pragma unroll
            for (int r = 0; r < 4; ++r)
                if (okr[r])
                    C[(size_t)grow[r] * 128 + colb] = __float2half_rn(acc[ct][r]);
        }
        return;
    }
    const int t = threadIdx.x;
    gbase[t] = ghist[(size_t)t * nb + blockIdx.x];
    lcur[t] = 0;                       // used as histogram first
    __syncthreads();
    const int base = blockIdx.x * SORT_ITEMS;
    const int end = min(base + SORT_ITEMS, total);
    const int cnt = end - base;

    u64 it[16];
    bool ok[16];
#pragma unroll
    for (int j = 0; j < 16; ++j) {
        const int i = base + t + j * 256;
        ok[j] = i < end;
        it[j] = ok[j] ? el[i] : 0;
        if (ok[j]) atomicAdd(&lcur[(u32)(it[j] >> 56)], 1u);
    }
    __syncthreads();
    const u32 v = lcur[t];
    lbase[t] = v;
    __syncthreads();
    for (int off = 1; off < 256; off <<= 1) {
        u32 u = (t >= off) ? lbase[t - off] : 0;
        __syncthreads();
        lbase[t] += u;
        __syncthreads();
    }
    const u32 excl = lbase[t] - v;     // exclusive local base for digit t
    __syncthreads();
    lbase[t] = excl;
    lcur[t] = excl;
    __syncthreads();
#pragma unroll
    for (int j = 0; j < 16; ++j) {
        if (ok[j]) {
            const u32 d = (u32)(it[j] >> 56);
            const u32 p = atomicAdd(&lcur[d], 1u);
            buf[p] = it[j];
        }
    }
    __syncthreads();
    for (int i = t; i < cnt; i += 256) {
        const u64 e = buf[i];
        const u32 d = (u32)(e >> 56);
        out[gbase[d] + i - lbase[d]] = e;
    }
}

// ---------------- merged pass 2 + gemm1 back half ----------------
// blocks [0, ngroups): quarter-private counting sort (1024 thr).
// blocks [ngroups, ...): 16-wave MFMA tiles, rows rowoff + gb*256.
__global__ __launch_bounds__(1024) void p2_gemm(
        const u64* __restrict__ in, u64* __restrict__ out,
        const u32* __restrict__ dbase,
        int* __restrict__ offs, float* __restrict__ dinv, int n, int ngroups,
        const float* __restrict__ x, const __half* __restrict__ Wh,
        __half* __restrict__ C, int rowoff) {
    if ((int)blockIdx.x < ngroups) {
        // ---- p2 quarter-private sort ----
        const int t = threadIdx.x;
        const int q = t >> 8;          // quarter 0..3
        const int b = t & 255;
        const int base = (int)dbase[blockIdx.x];
        const int size = (int)dbase[blockIdx.x + 1] - base;
        __shared__ u32 hist[4][256];
        __shared__ u32 cur[4][256];
        __shared__ u32 s[256];
        __shared__ float wsum[4][256];
        hist[q][b] = 0;
        wsum[q][b] = 0.f;
        __syncthreads();
        for (int i = t; i < size; i += 1024)
            atomicAdd(&hist[q][(u32)(in[base + i] >> 48) & 0xFFu], 1u);
        __syncthreads();
        u32 v = 0;
        if (t < 256) {
            v = hist[0][b] + hist[1][b] + hist[2][b] + hist[3][b];
            s[b] = v;
        }
        __syncthreads();
        for (int off = 1; off < 256; off <<= 1) {
            u32 u = (t < 256 && b >= off) ? s[b - off] : 0;
            __syncthreads();
            if (t < 256) s[b] += u;
            __syncthreads();
        }
        u32 mystart = 0;
        if (t < 256) {
            mystart = (u32)base + s[b] - v;   // node (blockIdx*256+b)'s run start
            u32 c = mystart;
            cur[0][b] = c; c += hist[0][b];
            cur[1][b] = c; c += hist[1][b];
            cur[2][b] = c; c += hist[2][b];
            cur[3][b] = c;
        }
        __syncthreads();
        for (int i = t; i < size; i += 1024) {
            u64 e = in[base + i];
            u32 lo = (u32)(e >> 48) & 0xFFu;
            u32 p = atomicAdd(&cur[q][lo], 1u);
            out[p] = e;
            atomicAdd(&wsum[q][lo], __uint_as_float((u32)(e & 0xFFFFFFFFu)));
        }
        __syncthreads();
        const int node = blockIdx.x * 256 + b;
        if (t < 256 && node < n && v > 0) {
            offs[node] = (int)mystart;
            dinv[node] = rsqrtf(wsum[0][b] + wsum[1][b] + wsum[2][b] + wsum[3][b]);
            if (node == n - 1) offs[n] = (int)(mystart + v);
        }
    } else {
        // ---- gemm tile: 16 waves x 16 rows, BN=128, fp32 input ----
        const int gb = blockIdx.x - ngroups;
        const int wave = threadIdx.x >> 6;
        const int lane = threadIdx.x & 63;
        const int quad = lane >> 4;
        const int l16  = lane & 15;
        const int row0 = rowoff + gb * 256 + wave * 16;

        int arow = row0 + l16;
        if (arow > n - 1) arow = n - 1;

        floatx4 acc[8] = {};
#pragma unroll
        for (int kc = 0; kc < 4; ++kc) {
            const int kof = kc * 32 + quad * 8;
            const float* ap = x + (size_t)arow * K_DIM + kof;
            float4 f0 = *(const float4*)ap;
            float4 f1 = *(const float4*)(ap + 4);
            half8 af;
            af[0] = (_Float16)f0.x; af[1] = (_Float16)f0.y;
            af[2] = (_Float16)f0.z; af[3] = (_Float16)f0.w;
            af[4] = (_Float16)f1.x; af[5] = (_Float16)f1.y;
            af[6] = (_Float16)f1.z; af[7] = (_Float16)f1.w;
#pragma unroll
            for (int ct = 0; ct < 8; ++ct) {
                half8 bf = *(const half8*)(Wh + (size_t)(ct * 16 + l16) * K_DIM + kof);
                acc[ct] = __builtin_amdgcn_mfma_f32_16x16x32_f16(af, bf, acc[ct], 0, 0, 0);
            }
        }
        int grow[4];
        bool ok[4];
#pragma unroll
        for (int r = 0; r < 4; ++r) {
            grow[r] = row0 + quad * 4 + r;
            ok[r] = grow[r] < n;
        }
#pragma unroll
        for (int ct = 0; ct < 8; ++ct) {
            const int colb = ct * 16 + l16;
#pragma unroll
            for (int r = 0; r < 4; ++r)
                if (ok[r])
                    C[(size_t)grow[r] * 128 + colb] = __float2half_rn(acc[ct][r]);
        }
    }
}

// ---------------- MFMA GEMM (layers 2,3): C[n][o] = half(sum_k A[n][k]*W[o][k]) ----------------

template <int BN>
__global__ __launch_bounds__(256) void mfma_gemm(const __half* __restrict__ Ain,
                                                 const __half* __restrict__ Wh,
                                                 __half* __restrict__ C, int nrows) {
    constexpr int NT = BN / 16;
    const int wave = threadIdx.x >> 6;
    const int lane = threadIdx.x & 63;
    const int quad = lane >> 4;
    const int l16  = lane & 15;
    const int row0 = blockIdx.x * 64 + wave * 16;

    int arow = row0 + l16;
    if (arow > nrows - 1) arow = nrows - 1;

    floatx4 acc[NT] = {};

#pragma unroll
    for (int kc = 0; kc < 4; ++kc) {
        const int kof = kc * 32 + quad * 8;
        half8 af = *(const half8*)(Ain + (size_t)arow * K_DIM + kof);
#pragma unroll
        for (int ct = 0; ct < NT; ++ct) {
            half8 bf = *(const half8*)(Wh + (size_t)(ct * 16 + l16) * K_DIM + kof);
            acc[ct] = __builtin_amdgcn_mfma_f32_16x16x32_f16(af, bf, acc[ct], 0, 0, 0);
        }
    }

    int grow[4];
    bool ok[4];
#pragma unroll
    for (int r = 0; r < 4; ++r) {
        grow[r] = row0 + quad * 4 + r;
        ok[r] = grow[r] < nrows;
    }
#pragma unroll
    for (int ct = 0; ct < NT; ++ct) {
        const int colb = ct * 16 + l16;
#pragma unroll
        for (int r = 0; r < 4; ++r)
            if (ok[r])
                C[(size_t)grow[r] * BN + colb] = __float2half_rn(acc[ct][r]);
    }
}

// ---------------- aggregation ----------------
// out[i] = relu(bias + dinv[i] * sum_e (ew_e * dinv[src_e]) * m_raw[src_e])
// R21 form: masked-head + unrolled body with 4 independent gathers in flight.

template <int D, typename OUT>
__global__ __launch_bounds__(256) void agg_kernel(
    const __half* __restrict__ m, const int* __restrict__ offs,
    const int2* __restrict__ csr, const float* __restrict__ dinv,
    const float* __restrict__ bias, OUT* __restrict__ out, int n) {
    const int wid = threadIdx.x >> 6;
    const int lane = threadIdx.x & 63;
    const int node = (blockIdx.x << 2) + wid;
    if (node >= n) return;
    const int beg = offs[node];
    const int end = offs[node + 1];
    const int cnt = end - beg;          // >= 1 (self-loop)
    const half8* mrow = (const half8*)m;

    // one coalesced load fetches up to 64 csr entries for this node
    const int2 ev = csr[beg + min(lane, cnt - 1)];
    const int   sv = ev.y & 0xFFFF;
    const float ds = dinv[sv];                      // L2-hot (200KB table)
    const float wv = (lane < cnt) ? __int_as_float(ev.x) * ds : 0.f;
    const int nr = min(cnt, 64);

    float acc[8] = {0.f, 0.f, 0.f, 0.f, 0.f, 0.f, 0.f, 0.f};

    if constexpr (D == 128) {
        const int quad = lane >> 4;
        const int l16  = lane & 15;
        const int rem = nr & 15;
        if (rem) {
            // masked head: edges [0, rem) via slots {quad, 4+quad, 8+quad, 12+quad}
            float w0 = __shfl(wv, quad),      w1 = __shfl(wv, 4 + quad);
            float w2 = __shfl(wv, 8 + quad),  w3 = __shfl(wv, 12 + quad);
            int   s0 = __shfl(sv, quad),      s1 = __shfl(sv, 4 + quad);
            int   s2 = __shfl(sv, 8 + quad),  s3 = __shfl(sv, 12 + quad);
            w0 = (quad      < rem) ? w0 : 0.f;
            w1 = (4 + quad  < rem) ? w1 : 0.f;
            w2 = (8 + quad  < rem) ? w2 : 0.f;
            w3 = (12 + quad < rem) ? w3 : 0.f;
            half8 h0 = mrow[(size_t)s0 * 16 + l16];
            half8 h1 = mrow[(size_t)s1 * 16 + l16];
            half8 h2 = mrow[(size_t)s2 * 16 + l16];
            half8 h3 = mrow[(size_t)s3 * 16 + l16];
#pragma unroll
            for (int i = 0; i < 8; ++i) {
                acc[i] = fmaf(w0, (float)h0[i], acc[i]);
                acc[i] = fmaf(w1, (float)h1[i], acc[i]);
                acc[i] = fmaf(w2, (float)h2[i], acc[i]);
                acc[i] = fmaf(w3, (float)h3[i], acc[i]);
            }
        }
        for (int k = rem; k < nr; k += 16) {
            float w0 = __shfl(wv, k + quad),      w1 = __shfl(wv, k + 4 + quad);
            float w2 = __shfl(wv, k + 8 + quad),  w3 = __shfl(wv, k + 12 + quad);
            int   s0 = __shfl(sv, k + quad),      s1 = __shfl(sv, k + 4 + quad);
            int   s2 = __shfl(sv, k + 8 + quad),  s3 = __shfl(sv, k + 12 + quad);
            half8 h0 = mrow[(size_t)s0 * 16 + l16];
            half8 h1 = mrow[(size_t)s1 * 16 + l16];
            half8 h2 = mrow[(size_t)s2 * 16 + l16];
            half8 h3 = mrow[(size_t)s3 * 16 + l16];
#pragma unroll
            for (int i = 0; i < 8; ++i) {
                acc[i] = fmaf(w0, (float)h0[i], acc[i]);
                acc[i] = fmaf(w1, (float)h1[i], acc[i]);
                acc[i] = fmaf(w2, (float)h2[i], acc[i]);
                acc[i] = fmaf(w3, (float)h3[i], acc[i]);
            }
        }
        // rare: degree > 64 tail, per-quad strided
        for (int k = beg + 64 + quad; k < end; k += 4) {
            const int2 e0 = csr[k];
            const int  s0 = e0.y & 0xFFFF;
            const float w0 = __int_as_float(e0.x) * dinv[s0];
            half8 hv = mrow[(size_t)s0 * 16 + l16];
#pragma unroll
            for (int i = 0; i < 8; ++i)
                acc[i] = fmaf(w0, (float)hv[i], acc[i]);
        }
#pragma unroll
        for (int i = 0; i < 8; ++i) {
            acc[i] += __shfl_xor(acc[i], 16);
            acc[i] += __shfl_xor(acc[i], 32);
        }
        if (quad == 0) {
            const float dv = dinv[node];
            const float4 b0 = *(const float4*)(bias + l16 * 8);
            const float4 b1 = *(const float4*)(bias + l16 * 8 + 4);
            const float bb[8] = {b0.x, b0.y, b0.z, b0.w, b1.x, b1.y, b1.z, b1.w};
            half8 ho;
#pragma unroll
            for (int i = 0; i < 8; ++i)
                ho[i] = (_Float16)fmaxf(acc[i] * dv + bb[i], 0.f);
            *(half8*)((__half*)out + (size_t)node * 128 + l16 * 8) = ho;
        }
    } else {
        // D == 64
        const int oct = lane >> 3;
        const int l8  = lane & 7;
        const int rem = nr & 31;
        if (rem) {
            // masked head: edges [0, rem) via slots {oct, 8+oct, 16+oct, 24+oct}
            float w0 = __shfl(wv, oct),       w1 = __shfl(wv, 8 + oct);
            float w2 = __shfl(wv, 16 + oct),  w3 = __shfl(wv, 24 + oct);
            int   s0 = __shfl(sv, oct),       s1 = __shfl(sv, 8 + oct);
            int   s2 = __shfl(sv, 16 + oct),  s3 = __shfl(sv, 24 + oct);
            w0 = (oct      < rem) ? w0 : 0.f;
            w1 = (8 + oct  < rem) ? w1 : 0.f;
            w2 = (16 + oct < rem) ? w2 : 0.f;
            w3 = (24 + oct < rem) ? w3 : 0.f;
            half8 h0 = mrow[(size_t)s0 * 8 + l8];
            half8 h1 = mrow[(size_t)s1 * 8 + l8];
            half8 h2 = mrow[(size_t)s2 * 8 + l8];
            half8 h3 = mrow[(size_t)s3 * 8 + l8];
#pragma unroll
            for (int i = 0; i < 8; ++i) {
                acc[i] = fmaf(w0, (float)h0[i], acc[i]);
                acc[i] = fmaf(w1, (float)h1[i], acc[i]);
                acc[i] = fmaf(w2, (float)h2[i], acc[i]);
                acc[i] = fmaf(w3, (float)h3[i], acc[i]);
            }
        }
        for (int k = rem; k < nr; k += 32) {
            float w0 = __shfl(wv, k + oct),       w1 = __shfl(wv, k + 8 + oct);
            float w2 = __shfl(wv, k + 16 + oct),  w3 = __shfl(wv, k + 24 + oct);
            int   s0 = __shfl(sv, k + oct),       s1 = __shfl(sv, k + 8 + oct);
            int   s2 = __shfl(sv, k + 16 + oct),  s3 = __shfl(sv, k + 24 + oct);
            half8 h0 = mrow[(size_t)s0 * 8 + l8];
            half8 h1 = mrow[(size_t)s1 * 8 + l8];
            half8 h2 = mrow[(size_t)s2 * 8 + l8];
            half8 h3 = mrow[(size_t)s3 * 8 + l8];
#pragma unroll
            for (int i = 0; i < 8; ++i) {
                acc[i] = fmaf(w0, (float)h0[i], acc[i]);
                acc[i] = fmaf(w1, (float)h1[i], acc[i]);
                acc[i] = fmaf(w2, (float)h2[i], acc[i]);
                acc[i] = fmaf(w3, (float)h3[i], acc[i]);
            }
        }
        for (int k = beg + 64 + oct; k < end; k += 8) {
            const int2 e0 = csr[k];
            const int  s0 = e0.y & 0xFFFF;
            const float w0 = __int_as_float(e0.x) * dinv[s0];
            half8 hv = mrow[(size_t)s0 * 8 + l8];
#pragma unroll
            for (int i = 0; i < 8; ++i)
                acc[i] = fmaf(w0, (float)hv[i], acc[i]);
        }
#pragma unroll
        for (int i = 0; i < 8; ++i) {
            acc[i] += __shfl_xor(acc[i], 8);
            acc[i] += __shfl_xor(acc[i], 16);
            acc[i] += __shfl_xor(acc[i], 32);
        }
        if (oct == 0) {
            const float dv = dinv[node];
            const float4 b0 = *(const float4*)(bias + l8 * 8);
            const float4 b1 = *(const float4*)(bias + l8 * 8 + 4);
            float4 v0, v1;
            v0.x = fmaxf(acc[0] * dv + b0.x, 0.f);
            v0.y = fmaxf(acc[1] * dv + b0.y, 0.f);
            v0.z = fmaxf(acc[2] * dv + b0.z, 0.f);
            v0.w = fmaxf(acc[3] * dv + b0.w, 0.f);
            v1.x = fmaxf(acc[4] * dv + b1.x, 0.f);
            v1.y = fmaxf(acc[5] * dv + b1.y, 0.f);
            v1.z = fmaxf(acc[6] * dv + b1.z, 0.f);
            v1.w = fmaxf(acc[7] * dv + b1.w, 0.f);
            float* op = (float*)out + (size_t)node * 64 + l8 * 8;
            *(float4*)op = v0;
            *(float4*)(op + 4) = v1;
        }
    }
}

// ---------------- launch ----------------

extern "C" void kernel_launch(void* const* d_in, const int* in_sizes, int n_in,
                              void* d_out, int out_size, void* d_ws, size_t ws_size,
                              hipStream_t stream) {
    const float* x  = (const float*)d_in[0];
    const int*   ei = (const int*)d_in[1];   // [2, E] int32
    const float* ew = (const float*)d_in[2];
    const float* W1 = (const float*)d_in[3];
    const float* b1 = (const float*)d_in[4];
    const float* W2 = (const float*)d_in[5];
    const float* b2 = (const float*)d_in[6];
    const float* W3 = (const float*)d_in[7];
    const float* b3 = (const float*)d_in[8];
    float* out = (float*)d_out;

    const int N = in_sizes[0] / K_DIM;      // 50000
    const int E = in_sizes[2];              // 800000
    const int* row = ei;                    // edge_index[0] (source)
    const int* col = ei + E;                // edge_index[1] (target / aggregation)

    const int total = E + N;                         // 850000
    const int nb = (total + SORT_ITEMS - 1) / SORT_ITEMS;   // 208
    const int ngroups = (N + 255) >> 8;              // 196 high-byte groups
    const int NW1 = 128 * 128, NW2 = 128 * 128, NW3 = 64 * 128;
    const int nwb = (NW1 + NW2 + NW3 + 255) / 256;   // 160 weight-convert blocks

    // workspace layout, 8B-aligned sections first
    u64* elA      = (u64*)d_ws;                                // total
    u64* elB      = elA + total;                               // total
    __half* m_buf = (__half*)(elB + total);                    // N*128 fp16
    __half* h_buf = m_buf + (size_t)N * K_DIM;                 // N*128 fp16
    __half* Wh    = h_buf + (size_t)N * K_DIM;                 // 40960 fp16
    u32* ghist    = (u32*)(Wh + NW1 + NW2 + NW3);              // 256*nb
    u32* dsum     = ghist + (size_t)256 * nb;                  // 256
    u32* dbase    = dsum + 256;                                // 257
    int* offs     = (int*)(dbase + 257);                       // N+1
    float* dinv   = (float*)(offs + N + 1);                    // N

    build_hist<<<nb + nwb, 256, 0, stream>>>(row, col, ew, elA, ghist, E, N, nb,
                                             W1, W2, W3, Wh, NW1, NW2, NW3);
    digit_sum<<<256, 256, 0, stream>>>(ghist, dsum, nb);
    digit_scan<<<256, 256, 0, stream>>>(ghist, dsum, dbase, nb);

    // gemm1 front half rides in the p1 launch: rows [0, g1rows)
    const int g1blocks = 392;                        // 64-row tiles
    const int g1rows = g1blocks * 64;                // 25088
    p1_gemm<<<nb + g1blocks, 256, 0, stream>>>(elA, ghist, elB, total, nb,
                                               x, Wh, m_buf, N);

    // gemm1 back half rides in the p2 launch: rows [g1rows, N)
    const int g2blocks = (N - g1rows + 255) / 256;   // 98 16-wave tiles
    p2_gemm<<<ngroups + g2blocks, 1024, 0, stream>>>(
        elB, elA, dbase, offs, dinv, N, ngroups, x, Wh, m_buf, g1rows);

    const int gemm_blocks = (N + 63) / 64;
    const int agg_blocks = (N + 3) / 4;
    const int2* csr = (const int2*)elA;

    // layer 1 agg: h = fp16(relu(dinv_n * sum (ew*dinv_s)*m_raw + b1))
    agg_kernel<128, __half><<<agg_blocks, 256, 0, stream>>>(m_buf, offs, csr, dinv, b1, h_buf, N);
    // layer 2
    mfma_gemm<128><<<gemm_blocks, 256, 0, stream>>>(h_buf, Wh + NW1, m_buf, N);
    agg_kernel<128, __half><<<agg_blocks, 256, 0, stream>>>(m_buf, offs, csr, dinv, b2, h_buf, N);
    // layer 3: F_OUT=64, write d_out (fp32) directly
    mfma_gemm<64><<<gemm_blocks, 256, 0, stream>>>(h_buf, Wh + NW1 + NW2, m_buf, N);
    agg_kernel<64, float><<<agg_blocks, 256, 0, stream>>>(m_buf, offs, csr, dinv, b3, out, N);
}